// Round 3
// baseline (791.252 us; speedup 1.0000x reference)
//
#include <hip/hip_runtime.h>
#include <math.h>

#define TT 8
#define NNODES 20000
#define NEDGES 320000
#define FDIM 128
#define HDIM 128
#define BGR 64
#define NCLS 16
#define GR 128   // gemm rows per block

__device__ __forceinline__ float lrelu(float x) { return fmaxf(x, 0.2f * x); }
__device__ __forceinline__ float sigmoidf(float x) { return 1.0f / (1.0f + __expf(-x)); }
__device__ __forceinline__ float tanh_fast(float x) {
  // tanh(x) = 1 - 2/(exp(2x)+1), exact in exact arithmetic; __expf err ~1e-6 rel
  return 1.0f - 2.0f / (__expf(2.0f * x) + 1.0f);
}

// ---------------- GEMM: h = x @ W  (M=T*N rows), epilogue: as=h@att_src, ad=h@att_dst
// 128x128 tile per block, 256 threads, 8x8 acc per thread.
__global__ __launch_bounds__(256) void k_gemm(
    const float* __restrict__ x, const float* __restrict__ W,
    const float* __restrict__ att_s, const float* __restrict__ att_d,
    float* __restrict__ h, float* __restrict__ as_, float* __restrict__ ad_) {
  __shared__ float xsT[32][GR + 4];   // [k][row], stride 132 floats
  __shared__ float ws[32][HDIM];      // [k][col] 16KB
  __shared__ float asl[GR], adl[GR];
  __shared__ float atts[HDIM], attd[HDIM];
  const int tid = threadIdx.x;
  const int row0 = blockIdx.x * GR;
  if (tid < GR) { asl[tid] = 0.f; adl[tid] = 0.f; }
  if (tid < 128) { atts[tid] = att_s[tid]; attd[tid] = att_d[tid]; }
  const int ty = tid >> 4;   // 0..15 -> 8 rows each
  const int tx = tid & 15;   // 0..15 -> 8 cols each
  float acc[8][8] = {};
  for (int kb = 0; kb < 4; ++kb) {
    __syncthreads();
    #pragma unroll
    for (int p = 0; p < 4; ++p) {   // x tile: 128 rows x 32 k, transposed store
      int idx = tid + p * 256;      // 0..1023
      int r = idx >> 3, k4 = idx & 7;
      float4 v = *(const float4*)(x + (size_t)(row0 + r) * FDIM + kb * 32 + k4 * 4);
      xsT[k4 * 4 + 0][r] = v.x; xsT[k4 * 4 + 1][r] = v.y;
      xsT[k4 * 4 + 2][r] = v.z; xsT[k4 * 4 + 3][r] = v.w;
    }
    #pragma unroll
    for (int p = 0; p < 4; ++p) {   // W tile
      int kr = (tid >> 5) + p * 8;
      int c4 = (tid & 31) * 4;
      *(float4*)(&ws[kr][c4]) = *(const float4*)(W + (size_t)(kb * 32 + kr) * HDIM + c4);
    }
    __syncthreads();
    #pragma unroll
    for (int k = 0; k < 32; ++k) {
      float a[8], bb[8];
      *(float4*)&a[0]  = *(const float4*)(&xsT[k][ty * 8]);
      *(float4*)&a[4]  = *(const float4*)(&xsT[k][ty * 8 + 4]);
      *(float4*)&bb[0] = *(const float4*)(&ws[k][tx * 8]);
      *(float4*)&bb[4] = *(const float4*)(&ws[k][tx * 8 + 4]);
      #pragma unroll
      for (int i = 0; i < 8; ++i)
        #pragma unroll
        for (int j = 0; j < 8; ++j)
          acc[i][j] += a[i] * bb[j];
    }
  }
  float av[8], dv[8];
  *(float4*)&av[0] = *(const float4*)(&atts[tx * 8]);
  *(float4*)&av[4] = *(const float4*)(&atts[tx * 8 + 4]);
  *(float4*)&dv[0] = *(const float4*)(&attd[tx * 8]);
  *(float4*)&dv[4] = *(const float4*)(&attd[tx * 8 + 4]);
  #pragma unroll
  for (int i = 0; i < 8; ++i) {
    int row = row0 + ty * 8 + i;
    *(float4*)(h + (size_t)row * HDIM + tx * 8)     = *(float4*)&acc[i][0];
    *(float4*)(h + (size_t)row * HDIM + tx * 8 + 4) = *(float4*)&acc[i][4];
    float ps = 0.f, pd = 0.f;
    #pragma unroll
    for (int j = 0; j < 8; ++j) { ps += acc[i][j] * av[j]; pd += acc[i][j] * dv[j]; }
    atomicAdd(&asl[ty * 8 + i], ps);
    atomicAdd(&adl[ty * 8 + i], pd);
  }
  __syncthreads();
  if (tid < GR) { as_[row0 + tid] = asl[tid]; ad_[row0 + tid] = adl[tid]; }
}

// ---------------- CSR build
__global__ void k_hist(const int* __restrict__ ei, int* __restrict__ cnt) {
  int g = blockIdx.x * 256 + threadIdx.x;  // over T*E
  int t = g / NEDGES, e = g - t * NEDGES;
  int dst = ei[(size_t)t * 2 * NEDGES + NEDGES + e];
  atomicAdd(&cnt[t * NNODES + dst], 1);
}

__global__ __launch_bounds__(256) void k_scan(const int* __restrict__ cnt, int* __restrict__ offs) {
  const int t = blockIdx.x;
  const int tid = threadIdx.x;
  const int SPAN = 79;  // 79*256 >= 20000
  __shared__ int sums[256];
  int lo = tid * SPAN, hi = min(lo + SPAN, NNODES);
  int s = 0;
  for (int i = lo; i < hi; ++i) s += cnt[t * NNODES + i];
  sums[tid] = s;
  __syncthreads();
  for (int off = 1; off < 256; off <<= 1) {
    int add = (tid >= off) ? sums[tid - off] : 0;
    __syncthreads();
    sums[tid] += add;
    __syncthreads();
  }
  int run = sums[tid] - s;  // exclusive base
  for (int i = lo; i < hi; ++i) { offs[t * NNODES + i] = run; run += cnt[t * NNODES + i]; }
}

__global__ void k_scatter(const int* __restrict__ ei, int* __restrict__ offs, int* __restrict__ csr) {
  int g = blockIdx.x * 256 + threadIdx.x;
  int t = g / NEDGES, e = g - t * NEDGES;
  int src = ei[(size_t)t * 2 * NEDGES + e];
  int dst = ei[(size_t)t * 2 * NEDGES + NEDGES + e];
  int pos = atomicAdd(&offs[t * NNODES + dst], 1);
  csr[(size_t)t * NEDGES + pos] = src;
}

// ---------------- batch segment starts (batch is sorted)
__global__ void k_starts(const int* __restrict__ batch, int* __restrict__ starts) {
  int n = blockIdx.x * 256 + threadIdx.x;
  if (n >= NNODES) return;
  int b = batch[n];
  if (n == 0) { for (int bb = 0; bb <= b; ++bb) starts[bb] = 0; }
  else { int pb = batch[n - 1]; for (int bb = pb + 1; bb <= b; ++bb) starts[bb] = n; }
  if (n == NNODES - 1) { for (int bb = b + 1; bb <= BGR; ++bb) starts[bb] = NNODES; }
}

// ---------------- per-node softmax-aggregate (wave per node) + fused pooling
// t = blockIdx & 7 pins each timestep's h[t] gather set to one XCD's L2.
__global__ __launch_bounds__(256) void k_aggr(
    const float* __restrict__ h, const float* __restrict__ as_, const float* __restrict__ ad_,
    const int* __restrict__ cnt, const int* __restrict__ offs, const int* __restrict__ csr,
    const int* __restrict__ batch, const float* __restrict__ bias,
    float* __restrict__ pooled) {
  __shared__ float pacc[4][128];
  __shared__ int sidx[4][64];
  __shared__ float sw[4][64];
  __shared__ int wb[4];
  const int tid = threadIdx.x;
  const int w = tid >> 6, lane = tid & 63;
  const int blk = blockIdx.x;
  const int t = blk & 7;             // XCD-pinned timestep (8 XCDs == TT)
  const int n = (blk >> 3) * 4 + w;
  const int tn = t * NNODES + n;
  const int deg = cnt[tn];
  const int end = offs[tn];          // after scatter, offs holds segment end
  const int start = end - deg;
  const float adn = ad_[tn];
  const float wself = __expf(lrelu(as_[tn] + adn));
  const int* ecsr = csr + (size_t)t * NEDGES;
  const float* asb = as_ + (size_t)t * NNODES;
  const float2* h2 = (const float2*)(h + (size_t)t * NNODES * HDIM);  // row stride 64

  float2 sv = h2[(size_t)n * 64 + lane];
  float accx = wself * sv.x, accy = wself * sv.y;
  float sp = 0.f;

  for (int base = start; base < end; base += 64) {
    const int c = min(64, end - base);
    if (lane < c) {
      int s = ecsr[base + lane];
      float wv = __expf(lrelu(asb[s] + adn));
      sidx[w][lane] = s;
      sw[w][lane] = wv;
      sp += wv;
    }
    // same-wave LDS produce->consume: program order within wave, no barrier needed
    int j = 0;
    for (; j + 2 <= c; j += 2) {
      int s0 = sidx[w][j], s1 = sidx[w][j + 1];
      float w0 = sw[w][j], w1 = sw[w][j + 1];
      float2 v0 = h2[(size_t)s0 * 64 + lane];
      float2 v1 = h2[(size_t)s1 * 64 + lane];
      accx += w0 * v0.x + w1 * v1.x;
      accy += w0 * v0.y + w1 * v1.y;
    }
    if (j < c) {
      int s0 = sidx[w][j];
      float w0 = sw[w][j];
      float2 v0 = h2[(size_t)s0 * 64 + lane];
      accx += w0 * v0.x;
      accy += w0 * v0.y;
    }
  }
  #pragma unroll
  for (int o = 32; o > 0; o >>= 1) sp += __shfl_xor(sp, o);
  const float inv = 1.0f / (sp + wself);

  pacc[w][2 * lane]     = accx * inv + bias[2 * lane];
  pacc[w][2 * lane + 1] = accy * inv + bias[2 * lane + 1];
  if (lane == 0) wb[w] = batch[n];
  __syncthreads();
  // sorted-adjacent merge of the 4 node slots
  if (tid < 128 && wb[3] == wb[2]) pacc[2][tid] += pacc[3][tid];
  __syncthreads();
  if (tid < 128 && wb[2] == wb[1]) pacc[1][tid] += pacc[2][tid];
  __syncthreads();
  if (tid < 128 && wb[1] == wb[0]) pacc[0][tid] += pacc[1][tid];
  __syncthreads();
  #pragma unroll
  for (int it = tid; it < 512; it += 256) {
    int ww = it >> 7, d = it & 127;
    bool root = (ww == 0) || (wb[ww] != wb[ww - 1]);
    if (root) atomicAdd(&pooled[((size_t)t * BGR + wb[ww]) * HDIM + d], pacc[ww][d]);
  }
}

// ---------------- LSTM over T + fused FC (one block per batch row b)
// 512 threads = 1 gate each. Weight row held in 32 float4 REGISTERS (statically
// indexed, fully unrolled). W_ih pass precomputes gx[0..7] (input contribution
// for all timesteps), then regs are reloaded with W_hh for the recurrence.
__global__ __launch_bounds__(512, 2) void k_lstm_fc(
    const float* __restrict__ pooled, const int* __restrict__ starts,
    const float* __restrict__ W_ih, const float* __restrict__ W_hh,
    const float* __restrict__ b_ih, const float* __restrict__ b_hh,
    const float* __restrict__ z, const float* __restrict__ fc_W,
    const float* __restrict__ fc_b, float* __restrict__ out) {
  const int b = blockIdx.x;
  const int g = threadIdx.x;   // gate index 0..511 (i,f,g,o blocks of 128)
  __shared__ float hv[128], cv[128], gates[512];
  __shared__ float pool8[TT][128];
  __shared__ float fcp[16][17];
  const int cntb = starts[b + 1] - starts[b];
  const float invc = 1.0f / (float)max(cntb, 1);
  #pragma unroll
  for (int i = 0; i < 2; ++i) {
    int idx = g + i * 512;           // 0..1023
    int t = idx >> 7, k = idx & 127;
    pool8[t][k] = pooled[((size_t)t * BGR + b) * HDIM + k] * invc;
  }
  if (g < 128) { hv[g] = 0.f; cv[g] = 0.f; }

  float4 w4[32];
  {
    const float4* wi = (const float4*)(W_ih + (size_t)g * HDIM);
    #pragma unroll
    for (int k4 = 0; k4 < 32; ++k4) w4[k4] = wi[k4];
  }
  __syncthreads();   // pool8, hv, cv ready

  float gx[8];
  const float bsum = b_ih[g] + b_hh[g];
  #pragma unroll
  for (int t = 0; t < TT; ++t) {
    float s = bsum;
    #pragma unroll
    for (int k4 = 0; k4 < 32; ++k4) {
      float4 p = *(const float4*)(&pool8[t][k4 * 4]);
      s += w4[k4].x * p.x + w4[k4].y * p.y + w4[k4].z * p.z + w4[k4].w * p.w;
    }
    gx[t] = s;
  }
  {
    const float4* wh = (const float4*)(W_hh + (size_t)g * HDIM);
    #pragma unroll
    for (int k4 = 0; k4 < 32; ++k4) w4[k4] = wh[k4];
  }
  #pragma unroll
  for (int t = 0; t < TT; ++t) {
    float s = gx[t];
    #pragma unroll
    for (int k4 = 0; k4 < 32; ++k4) {
      float4 hh = *(const float4*)(&hv[k4 * 4]);
      s += w4[k4].x * hh.x + w4[k4].y * hh.y + w4[k4].z * hh.z + w4[k4].w * hh.w;
    }
    gates[g] = s;
    __syncthreads();
    if (g < 128) {
      float ig = sigmoidf(gates[g]);
      float fg = sigmoidf(gates[128 + g]);
      float gc = tanh_fast(gates[256 + g]);
      float og = sigmoidf(gates[384 + g]);
      float c = fg * cv[g] + ig * gc;
      cv[g] = c;
      hv[g] = og * tanh_fast(c);
    }
    __syncthreads();
  }
  // fused FC: out[b][c] = concat(hv, z[b]) . fc_W[c] + fc_b[c]
  if (g < 256) {
    const int c = g >> 4, kp = g & 15;
    float s = 0.f;
    for (int k = kp * 16; k < kp * 16 + 16; ++k) {
      float v = (k < 128) ? hv[k] : z[(size_t)b * HDIM + (k - 128)];
      s += v * fc_W[(size_t)c * 256 + k];
    }
    fcp[c][kp] = s;
  }
  __syncthreads();
  if (g < 16) {
    float r = fc_b[g];
    #pragma unroll
    for (int k = 0; k < 16; ++k) r += fcp[g][k];
    out[(size_t)b * NCLS + g] = r;
  }
}

extern "C" void kernel_launch(void* const* d_in, const int* in_sizes, int n_in,
                              void* d_out, int out_size, void* d_ws, size_t ws_size,
                              hipStream_t stream) {
  const float* x       = (const float*)d_in[0];
  const int*   ei      = (const int*)d_in[1];
  const int*   batch   = (const int*)d_in[2];
  const float* z       = (const float*)d_in[3];
  const float* gat_W   = (const float*)d_in[4];
  const float* att_src = (const float*)d_in[5];
  const float* att_dst = (const float*)d_in[6];
  const float* gat_bias= (const float*)d_in[7];
  const float* W_ih    = (const float*)d_in[8];
  const float* W_hh    = (const float*)d_in[9];
  const float* b_ih    = (const float*)d_in[10];
  const float* b_hh    = (const float*)d_in[11];
  const float* fc_W    = (const float*)d_in[12];
  const float* fc_b    = (const float*)d_in[13];
  float* out = (float*)d_out;

  char* ws = (char*)d_ws;
  size_t off = 0;
  auto alloc = [&](size_t bytes) {
    void* p = (void*)(ws + off);
    off += (bytes + 255) & ~(size_t)255;
    return p;
  };
  float* h      = (float*)alloc((size_t)TT * NNODES * HDIM * 4);  // 81.92 MB
  float* as_    = (float*)alloc((size_t)TT * NNODES * 4);
  float* ad_    = (float*)alloc((size_t)TT * NNODES * 4);
  int*   cnt    = (int*)alloc((size_t)TT * NNODES * 4);
  int*   offs   = (int*)alloc((size_t)TT * NNODES * 4);
  int*   csr    = (int*)alloc((size_t)TT * NEDGES * 4);            // 10.24 MB
  int*   starts = (int*)alloc((BGR + 1) * 4);
  float* pooled = (float*)alloc((size_t)TT * BGR * HDIM * 4);
  (void)ws_size; (void)in_sizes; (void)n_in; (void)out_size;

  hipMemsetAsync(cnt, 0, (size_t)TT * NNODES * 4, stream);
  hipMemsetAsync(pooled, 0, (size_t)TT * BGR * HDIM * 4, stream);

  k_gemm<<<(TT * NNODES) / GR, 256, 0, stream>>>(x, gat_W, att_src, att_dst, h, as_, ad_);
  k_hist<<<(TT * NEDGES) / 256, 256, 0, stream>>>(ei, cnt);
  k_scan<<<TT, 256, 0, stream>>>(cnt, offs);
  k_scatter<<<(TT * NEDGES) / 256, 256, 0, stream>>>(ei, offs, csr);
  k_starts<<<(NNODES + 255) / 256, 256, 0, stream>>>(batch, starts);
  k_aggr<<<TT * (NNODES / 4), 256, 0, stream>>>(h, as_, ad_, cnt, offs, csr, batch, gat_bias, pooled);
  k_lstm_fc<<<BGR, 512, 0, stream>>>(pooled, starts, W_ih, W_hh, b_ih, b_hh, z, fc_W, fc_b, out);
}

// Round 4
// 763.821 us; speedup vs baseline: 1.0359x; 1.0359x over previous
//
#include <hip/hip_runtime.h>
#include <math.h>

#define TT 8
#define NNODES 20000
#define NEDGES 320000
#define FDIM 128
#define HDIM 128
#define BGR 64
#define NCLS 16
#define GR 128   // gemm rows per block

__device__ __forceinline__ float lrelu(float x) { return fmaxf(x, 0.2f * x); }
__device__ __forceinline__ float sigmoidf(float x) { return 1.0f / (1.0f + __expf(-x)); }
__device__ __forceinline__ float tanh_fast(float x) {
  // tanh(x) = 1 - 2/(exp(2x)+1); __expf err ~1e-6 rel
  return 1.0f - 2.0f / (__expf(2.0f * x) + 1.0f);
}

// ---------------- GEMM: h = x @ W  (M=T*N rows), epilogue: as=h@att_src, ad=h@att_dst
// 128x128 tile per block, 256 threads, 8x8 acc per thread.
__global__ __launch_bounds__(256) void k_gemm(
    const float* __restrict__ x, const float* __restrict__ W,
    const float* __restrict__ att_s, const float* __restrict__ att_d,
    float* __restrict__ h, float* __restrict__ as_, float* __restrict__ ad_) {
  __shared__ float xsT[32][GR + 4];   // [k][row], stride 132 floats
  __shared__ float ws[32][HDIM];      // [k][col] 16KB
  __shared__ float asl[GR], adl[GR];
  __shared__ float atts[HDIM], attd[HDIM];
  const int tid = threadIdx.x;
  const int row0 = blockIdx.x * GR;
  if (tid < GR) { asl[tid] = 0.f; adl[tid] = 0.f; }
  if (tid < 128) { atts[tid] = att_s[tid]; attd[tid] = att_d[tid]; }
  const int ty = tid >> 4;   // 0..15 -> 8 rows each
  const int tx = tid & 15;   // 0..15 -> 8 cols each
  float acc[8][8] = {};
  for (int kb = 0; kb < 4; ++kb) {
    __syncthreads();
    #pragma unroll
    for (int p = 0; p < 4; ++p) {   // x tile: 128 rows x 32 k, transposed store
      int idx = tid + p * 256;      // 0..1023
      int r = idx >> 3, k4 = idx & 7;
      float4 v = *(const float4*)(x + (size_t)(row0 + r) * FDIM + kb * 32 + k4 * 4);
      xsT[k4 * 4 + 0][r] = v.x; xsT[k4 * 4 + 1][r] = v.y;
      xsT[k4 * 4 + 2][r] = v.z; xsT[k4 * 4 + 3][r] = v.w;
    }
    #pragma unroll
    for (int p = 0; p < 4; ++p) {   // W tile
      int kr = (tid >> 5) + p * 8;
      int c4 = (tid & 31) * 4;
      *(float4*)(&ws[kr][c4]) = *(const float4*)(W + (size_t)(kb * 32 + kr) * HDIM + c4);
    }
    __syncthreads();
    #pragma unroll
    for (int k = 0; k < 32; ++k) {
      float a[8], bb[8];
      *(float4*)&a[0]  = *(const float4*)(&xsT[k][ty * 8]);
      *(float4*)&a[4]  = *(const float4*)(&xsT[k][ty * 8 + 4]);
      *(float4*)&bb[0] = *(const float4*)(&ws[k][tx * 8]);
      *(float4*)&bb[4] = *(const float4*)(&ws[k][tx * 8 + 4]);
      #pragma unroll
      for (int i = 0; i < 8; ++i)
        #pragma unroll
        for (int j = 0; j < 8; ++j)
          acc[i][j] += a[i] * bb[j];
    }
  }
  float av[8], dv[8];
  *(float4*)&av[0] = *(const float4*)(&atts[tx * 8]);
  *(float4*)&av[4] = *(const float4*)(&atts[tx * 8 + 4]);
  *(float4*)&dv[0] = *(const float4*)(&attd[tx * 8]);
  *(float4*)&dv[4] = *(const float4*)(&attd[tx * 8 + 4]);
  #pragma unroll
  for (int i = 0; i < 8; ++i) {
    int row = row0 + ty * 8 + i;
    *(float4*)(h + (size_t)row * HDIM + tx * 8)     = *(float4*)&acc[i][0];
    *(float4*)(h + (size_t)row * HDIM + tx * 8 + 4) = *(float4*)&acc[i][4];
    float ps = 0.f, pd = 0.f;
    #pragma unroll
    for (int j = 0; j < 8; ++j) { ps += acc[i][j] * av[j]; pd += acc[i][j] * dv[j]; }
    atomicAdd(&asl[ty * 8 + i], ps);
    atomicAdd(&adl[ty * 8 + i], pd);
  }
  __syncthreads();
  if (tid < GR) { as_[row0 + tid] = asl[tid]; ad_[row0 + tid] = adl[tid]; }
}

// ---------------- CSR build
__global__ void k_hist(const int* __restrict__ ei, int* __restrict__ cnt) {
  int g = blockIdx.x * 256 + threadIdx.x;  // over T*E
  int t = g / NEDGES, e = g - t * NEDGES;
  int dst = ei[(size_t)t * 2 * NEDGES + NEDGES + e];
  atomicAdd(&cnt[t * NNODES + dst], 1);
}

__global__ __launch_bounds__(256) void k_scan(const int* __restrict__ cnt, int* __restrict__ offs) {
  const int t = blockIdx.x;
  const int tid = threadIdx.x;
  const int SPAN = 79;  // 79*256 >= 20000
  __shared__ int sums[256];
  int lo = tid * SPAN, hi = min(lo + SPAN, NNODES);
  int s = 0;
  for (int i = lo; i < hi; ++i) s += cnt[t * NNODES + i];
  sums[tid] = s;
  __syncthreads();
  for (int off = 1; off < 256; off <<= 1) {
    int add = (tid >= off) ? sums[tid - off] : 0;
    __syncthreads();
    sums[tid] += add;
    __syncthreads();
  }
  int run = sums[tid] - s;  // exclusive base
  for (int i = lo; i < hi; ++i) { offs[t * NNODES + i] = run; run += cnt[t * NNODES + i]; }
}

__global__ void k_scatter(const int* __restrict__ ei, int* __restrict__ offs, int* __restrict__ csr) {
  int g = blockIdx.x * 256 + threadIdx.x;
  int t = g / NEDGES, e = g - t * NEDGES;
  int src = ei[(size_t)t * 2 * NEDGES + e];
  int dst = ei[(size_t)t * 2 * NEDGES + NEDGES + e];
  int pos = atomicAdd(&offs[t * NNODES + dst], 1);
  csr[(size_t)t * NEDGES + pos] = src;
}

// ---------------- batch segment starts (batch is sorted)
__global__ void k_starts(const int* __restrict__ batch, int* __restrict__ starts) {
  int n = blockIdx.x * 256 + threadIdx.x;
  if (n >= NNODES) return;
  int b = batch[n];
  if (n == 0) { for (int bb = 0; bb <= b; ++bb) starts[bb] = 0; }
  else { int pb = batch[n - 1]; for (int bb = pb + 1; bb <= b; ++bb) starts[bb] = n; }
  if (n == NNODES - 1) { for (int bb = b + 1; bb <= BGR; ++bb) starts[bb] = NNODES; }
}

// ---------------- per-node softmax-aggregate (wave per node) + fused pooling
// t = blockIdx & 7 pins each timestep's h[t] gather set to one XCD's L2.
__global__ __launch_bounds__(256) void k_aggr(
    const float* __restrict__ h, const float* __restrict__ as_, const float* __restrict__ ad_,
    const int* __restrict__ cnt, const int* __restrict__ offs, const int* __restrict__ csr,
    const int* __restrict__ batch, const float* __restrict__ bias,
    float* __restrict__ pooled) {
  __shared__ float pacc[4][128];
  __shared__ int sidx[4][64];
  __shared__ float sw[4][64];
  __shared__ int wb[4];
  const int tid = threadIdx.x;
  const int w = tid >> 6, lane = tid & 63;
  const int blk = blockIdx.x;
  const int t = blk & 7;             // XCD-pinned timestep (8 XCDs == TT)
  const int n = (blk >> 3) * 4 + w;
  const int tn = t * NNODES + n;
  const int deg = cnt[tn];
  const int end = offs[tn];          // after scatter, offs holds segment end
  const int start = end - deg;
  const float adn = ad_[tn];
  const float wself = __expf(lrelu(as_[tn] + adn));
  const int* ecsr = csr + (size_t)t * NEDGES;
  const float* asb = as_ + (size_t)t * NNODES;
  const float2* h2 = (const float2*)(h + (size_t)t * NNODES * HDIM);  // row stride 64

  float2 sv = h2[(size_t)n * 64 + lane];
  float accx = wself * sv.x, accy = wself * sv.y;
  float sp = 0.f;

  for (int base = start; base < end; base += 64) {
    const int c = min(64, end - base);
    if (lane < c) {
      int s = ecsr[base + lane];
      float wv = __expf(lrelu(asb[s] + adn));
      sidx[w][lane] = s;
      sw[w][lane] = wv;
      sp += wv;
    }
    // same-wave LDS produce->consume: program order within wave, no barrier needed
    int j = 0;
    for (; j + 2 <= c; j += 2) {
      int s0 = sidx[w][j], s1 = sidx[w][j + 1];
      float w0 = sw[w][j], w1 = sw[w][j + 1];
      float2 v0 = h2[(size_t)s0 * 64 + lane];
      float2 v1 = h2[(size_t)s1 * 64 + lane];
      accx += w0 * v0.x + w1 * v1.x;
      accy += w0 * v0.y + w1 * v1.y;
    }
    if (j < c) {
      int s0 = sidx[w][j];
      float w0 = sw[w][j];
      float2 v0 = h2[(size_t)s0 * 64 + lane];
      accx += w0 * v0.x;
      accy += w0 * v0.y;
    }
  }
  #pragma unroll
  for (int o = 32; o > 0; o >>= 1) sp += __shfl_xor(sp, o);
  const float inv = 1.0f / (sp + wself);

  pacc[w][2 * lane]     = accx * inv + bias[2 * lane];
  pacc[w][2 * lane + 1] = accy * inv + bias[2 * lane + 1];
  if (lane == 0) wb[w] = batch[n];
  __syncthreads();
  // sorted-adjacent merge of the 4 node slots
  if (tid < 128 && wb[3] == wb[2]) pacc[2][tid] += pacc[3][tid];
  __syncthreads();
  if (tid < 128 && wb[2] == wb[1]) pacc[1][tid] += pacc[2][tid];
  __syncthreads();
  if (tid < 128 && wb[1] == wb[0]) pacc[0][tid] += pacc[1][tid];
  __syncthreads();
  #pragma unroll
  for (int it = tid; it < 512; it += 256) {
    int ww = it >> 7, d = it & 127;
    bool root = (ww == 0) || (wb[ww] != wb[ww - 1]);
    if (root) atomicAdd(&pooled[((size_t)t * BGR + wb[ww]) * HDIM + d], pacc[ww][d]);
  }
}

// ---------------- LSTM over T + fused FC (one block per batch row b)
// 1024 threads: thread = (gate g 0..511, k-half 0/1). Each thread holds HALF a
// weight row (16 float4 = 64 VGPR, statically indexed -> no spill at the
// 128-VGPR / 4-waves-per-SIMD cap). W_ih pass precomputes gx[0..7]; the same
// registers are then reloaded with W_hh for the recurrence. Halves combine
// through LDS each timestep.
__global__ __launch_bounds__(1024, 4) void k_lstm_fc(
    const float* __restrict__ pooled, const int* __restrict__ starts,
    const float* __restrict__ W_ih, const float* __restrict__ W_hh,
    const float* __restrict__ b_ih, const float* __restrict__ b_hh,
    const float* __restrict__ z, const float* __restrict__ fc_W,
    const float* __restrict__ fc_b, float* __restrict__ out) {
  const int b = blockIdx.x;
  const int tid = threadIdx.x;   // 0..1023
  const int g = tid & 511;       // gate index (i,f,g,o blocks of 128)
  const int half = tid >> 9;     // k-range [half*64, half*64+64)
  __shared__ float hv[128], cv[128];
  __shared__ float part[1024];
  __shared__ float pool8[TT][128];
  __shared__ float fcp[16][17];
  const int cntb = starts[b + 1] - starts[b];
  const float invc = 1.0f / (float)max(cntb, 1);
  {
    int t = tid >> 7, k = tid & 127;   // 1024 threads cover TT*128 exactly
    pool8[t][k] = pooled[((size_t)t * BGR + b) * HDIM + k] * invc;
  }
  if (tid < 128) { hv[tid] = 0.f; cv[tid] = 0.f; }

  float4 w4[16];
  {
    const float4* wi = (const float4*)(W_ih + (size_t)g * HDIM + half * 64);
    #pragma unroll
    for (int k4 = 0; k4 < 16; ++k4) w4[k4] = wi[k4];
  }
  const float bsum = (half == 0) ? (b_ih[g] + b_hh[g]) : 0.f;
  __syncthreads();   // pool8, hv, cv ready

  float gx[8];
  #pragma unroll
  for (int t = 0; t < TT; ++t) {
    float s = 0.f;
    #pragma unroll
    for (int k4 = 0; k4 < 16; ++k4) {
      float4 p = *(const float4*)(&pool8[t][half * 64 + k4 * 4]);
      s += w4[k4].x * p.x + w4[k4].y * p.y + w4[k4].z * p.z + w4[k4].w * p.w;
    }
    gx[t] = s + bsum;
  }
  {
    const float4* wh = (const float4*)(W_hh + (size_t)g * HDIM + half * 64);
    #pragma unroll
    for (int k4 = 0; k4 < 16; ++k4) w4[k4] = wh[k4];
  }
  #pragma unroll
  for (int t = 0; t < TT; ++t) {
    float s = gx[t];
    #pragma unroll
    for (int k4 = 0; k4 < 16; ++k4) {
      float4 hh = *(const float4*)(&hv[half * 64 + k4 * 4]);
      s += w4[k4].x * hh.x + w4[k4].y * hh.y + w4[k4].z * hh.z + w4[k4].w * hh.w;
    }
    part[tid] = s;
    __syncthreads();
    if (tid < 128) {
      float ig = sigmoidf(part[tid]       + part[tid + 512]);
      float fg = sigmoidf(part[128 + tid] + part[640 + tid]);
      float gc = tanh_fast(part[256 + tid] + part[768 + tid]);
      float og = sigmoidf(part[384 + tid] + part[896 + tid]);
      float c = fg * cv[tid] + ig * gc;
      cv[tid] = c;
      hv[tid] = og * tanh_fast(c);
    }
    __syncthreads();
  }
  // fused FC: out[b][c] = concat(hv, z[b]) . fc_W[c] + fc_b[c]
  if (tid < 256) {
    const int c = tid >> 4, kp = tid & 15;
    float s = 0.f;
    for (int k = kp * 16; k < kp * 16 + 16; ++k) {
      float v = (k < 128) ? hv[k] : z[(size_t)b * HDIM + (k - 128)];
      s += v * fc_W[(size_t)c * 256 + k];
    }
    fcp[c][kp] = s;
  }
  __syncthreads();
  if (tid < 16) {
    float r = fc_b[tid];
    #pragma unroll
    for (int k = 0; k < 16; ++k) r += fcp[tid][k];
    out[(size_t)b * NCLS + tid] = r;
  }
}

extern "C" void kernel_launch(void* const* d_in, const int* in_sizes, int n_in,
                              void* d_out, int out_size, void* d_ws, size_t ws_size,
                              hipStream_t stream) {
  const float* x       = (const float*)d_in[0];
  const int*   ei      = (const int*)d_in[1];
  const int*   batch   = (const int*)d_in[2];
  const float* z       = (const float*)d_in[3];
  const float* gat_W   = (const float*)d_in[4];
  const float* att_src = (const float*)d_in[5];
  const float* att_dst = (const float*)d_in[6];
  const float* gat_bias= (const float*)d_in[7];
  const float* W_ih    = (const float*)d_in[8];
  const float* W_hh    = (const float*)d_in[9];
  const float* b_ih    = (const float*)d_in[10];
  const float* b_hh    = (const float*)d_in[11];
  const float* fc_W    = (const float*)d_in[12];
  const float* fc_b    = (const float*)d_in[13];
  float* out = (float*)d_out;

  char* ws = (char*)d_ws;
  size_t off = 0;
  auto alloc = [&](size_t bytes) {
    void* p = (void*)(ws + off);
    off += (bytes + 255) & ~(size_t)255;
    return p;
  };
  float* h      = (float*)alloc((size_t)TT * NNODES * HDIM * 4);  // 81.92 MB
  float* as_    = (float*)alloc((size_t)TT * NNODES * 4);
  float* ad_    = (float*)alloc((size_t)TT * NNODES * 4);
  int*   cnt    = (int*)alloc((size_t)TT * NNODES * 4);
  int*   offs   = (int*)alloc((size_t)TT * NNODES * 4);
  int*   csr    = (int*)alloc((size_t)TT * NEDGES * 4);            // 10.24 MB
  int*   starts = (int*)alloc((BGR + 1) * 4);
  float* pooled = (float*)alloc((size_t)TT * BGR * HDIM * 4);
  (void)ws_size; (void)in_sizes; (void)n_in; (void)out_size;

  hipMemsetAsync(cnt, 0, (size_t)TT * NNODES * 4, stream);
  hipMemsetAsync(pooled, 0, (size_t)TT * BGR * HDIM * 4, stream);

  k_gemm<<<(TT * NNODES) / GR, 256, 0, stream>>>(x, gat_W, att_src, att_dst, h, as_, ad_);
  k_hist<<<(TT * NEDGES) / 256, 256, 0, stream>>>(ei, cnt);
  k_scan<<<TT, 256, 0, stream>>>(cnt, offs);
  k_scatter<<<(TT * NEDGES) / 256, 256, 0, stream>>>(ei, offs, csr);
  k_starts<<<(NNODES + 255) / 256, 256, 0, stream>>>(batch, starts);
  k_aggr<<<TT * (NNODES / 4), 256, 0, stream>>>(h, as_, ad_, cnt, offs, csr, batch, gat_bias, pooled);
  k_lstm_fc<<<BGR, 1024, 0, stream>>>(pooled, starts, W_ih, W_hh, b_ih, b_hh, z, fc_W, fc_b, out);
}

// Round 5
// 672.321 us; speedup vs baseline: 1.1769x; 1.1361x over previous
//
#include <hip/hip_runtime.h>
#include <math.h>

#define TT 8
#define NNODES 20000
#define NEDGES 320000
#define FDIM 128
#define HDIM 128
#define BGR 64
#define NCLS 16
#define GR 128   // gemm rows per block

__device__ __forceinline__ float lrelu(float x) { return fmaxf(x, 0.2f * x); }
__device__ __forceinline__ float sigmoidf(float x) { return 1.0f / (1.0f + __expf(-x)); }
__device__ __forceinline__ float tanh_fast(float x) {
  return 1.0f - 2.0f / (__expf(2.0f * x) + 1.0f);
}
__device__ __forceinline__ unsigned short f2bf(float f) {   // RNE
  unsigned int u = __float_as_uint(f);
  unsigned int r = (u + 0x7fff + ((u >> 16) & 1)) >> 16;
  return (unsigned short)r;
}
__device__ __forceinline__ float bf_lo(unsigned int u) { return __uint_as_float(u << 16); }
__device__ __forceinline__ float bf_hi(unsigned int u) { return __uint_as_float(u & 0xffff0000u); }

// ---------------- GEMM: h = x @ W (h stored bf16), epilogue: as=h@att_src, ad=h@att_dst
// 128x128 tile per block, 256 threads, 8x8 acc per thread.
__global__ __launch_bounds__(256) void k_gemm(
    const float* __restrict__ x, const float* __restrict__ W,
    const float* __restrict__ att_s, const float* __restrict__ att_d,
    unsigned short* __restrict__ hb, float* __restrict__ as_, float* __restrict__ ad_) {
  __shared__ float xsT[32][GR + 4];   // [k][row]
  __shared__ float ws[32][HDIM];      // [k][col]
  __shared__ float asl[GR], adl[GR];
  __shared__ float atts[HDIM], attd[HDIM];
  const int tid = threadIdx.x;
  const int row0 = blockIdx.x * GR;
  if (tid < GR) { asl[tid] = 0.f; adl[tid] = 0.f; }
  if (tid < 128) { atts[tid] = att_s[tid]; attd[tid] = att_d[tid]; }
  const int ty = tid >> 4;   // 0..15 -> 8 rows each
  const int tx = tid & 15;   // 0..15 -> 8 cols each
  float acc[8][8] = {};
  for (int kb = 0; kb < 4; ++kb) {
    __syncthreads();
    #pragma unroll
    for (int p = 0; p < 4; ++p) {   // x tile: 128 rows x 32 k, transposed store
      int idx = tid + p * 256;
      int r = idx >> 3, k4 = idx & 7;
      float4 v = *(const float4*)(x + (size_t)(row0 + r) * FDIM + kb * 32 + k4 * 4);
      xsT[k4 * 4 + 0][r] = v.x; xsT[k4 * 4 + 1][r] = v.y;
      xsT[k4 * 4 + 2][r] = v.z; xsT[k4 * 4 + 3][r] = v.w;
    }
    #pragma unroll
    for (int p = 0; p < 4; ++p) {   // W tile
      int kr = (tid >> 5) + p * 8;
      int c4 = (tid & 31) * 4;
      *(float4*)(&ws[kr][c4]) = *(const float4*)(W + (size_t)(kb * 32 + kr) * HDIM + c4);
    }
    __syncthreads();
    #pragma unroll
    for (int k = 0; k < 32; ++k) {
      float a[8], bb[8];
      *(float4*)&a[0]  = *(const float4*)(&xsT[k][ty * 8]);
      *(float4*)&a[4]  = *(const float4*)(&xsT[k][ty * 8 + 4]);
      *(float4*)&bb[0] = *(const float4*)(&ws[k][tx * 8]);
      *(float4*)&bb[4] = *(const float4*)(&ws[k][tx * 8 + 4]);
      #pragma unroll
      for (int i = 0; i < 8; ++i)
        #pragma unroll
        for (int j = 0; j < 8; ++j)
          acc[i][j] += a[i] * bb[j];
    }
  }
  float av[8], dv[8];
  *(float4*)&av[0] = *(const float4*)(&atts[tx * 8]);
  *(float4*)&av[4] = *(const float4*)(&atts[tx * 8 + 4]);
  *(float4*)&dv[0] = *(const float4*)(&attd[tx * 8]);
  *(float4*)&dv[4] = *(const float4*)(&attd[tx * 8 + 4]);
  #pragma unroll
  for (int i = 0; i < 8; ++i) {
    int row = row0 + ty * 8 + i;
    float ps = 0.f, pd = 0.f;
    #pragma unroll
    for (int j = 0; j < 8; ++j) { ps += acc[i][j] * av[j]; pd += acc[i][j] * dv[j]; }
    uint4 pk;
    pk.x = (unsigned int)f2bf(acc[i][0]) | ((unsigned int)f2bf(acc[i][1]) << 16);
    pk.y = (unsigned int)f2bf(acc[i][2]) | ((unsigned int)f2bf(acc[i][3]) << 16);
    pk.z = (unsigned int)f2bf(acc[i][4]) | ((unsigned int)f2bf(acc[i][5]) << 16);
    pk.w = (unsigned int)f2bf(acc[i][6]) | ((unsigned int)f2bf(acc[i][7]) << 16);
    *(uint4*)(hb + (size_t)row * HDIM + tx * 8) = pk;
    atomicAdd(&asl[ty * 8 + i], ps);
    atomicAdd(&adl[ty * 8 + i], pd);
  }
  __syncthreads();
  if (tid < GR) { as_[row0 + tid] = asl[tid]; ad_[row0 + tid] = adl[tid]; }
}

// ---------------- CSR build
__global__ void k_hist(const int* __restrict__ ei, int* __restrict__ cnt) {
  int g = blockIdx.x * 256 + threadIdx.x;
  int t = g / NEDGES, e = g - t * NEDGES;
  int dst = ei[(size_t)t * 2 * NEDGES + NEDGES + e];
  atomicAdd(&cnt[t * NNODES + dst], 1);
}

__global__ __launch_bounds__(256) void k_scan(const int* __restrict__ cnt, int* __restrict__ offs) {
  const int t = blockIdx.x;
  const int tid = threadIdx.x;
  const int SPAN = 79;
  __shared__ int sums[256];
  int lo = tid * SPAN, hi = min(lo + SPAN, NNODES);
  int s = 0;
  for (int i = lo; i < hi; ++i) s += cnt[t * NNODES + i];
  sums[tid] = s;
  __syncthreads();
  for (int off = 1; off < 256; off <<= 1) {
    int add = (tid >= off) ? sums[tid - off] : 0;
    __syncthreads();
    sums[tid] += add;
    __syncthreads();
  }
  int run = sums[tid] - s;
  for (int i = lo; i < hi; ++i) { offs[t * NNODES + i] = run; run += cnt[t * NNODES + i]; }
}

__global__ void k_scatter(const int* __restrict__ ei, int* __restrict__ offs, int* __restrict__ csr) {
  int g = blockIdx.x * 256 + threadIdx.x;
  int t = g / NEDGES, e = g - t * NEDGES;
  int src = ei[(size_t)t * 2 * NEDGES + e];
  int dst = ei[(size_t)t * 2 * NEDGES + NEDGES + e];
  int pos = atomicAdd(&offs[t * NNODES + dst], 1);
  csr[(size_t)t * NEDGES + pos] = src;
}

// ---------------- batch segment starts (batch is sorted)
__global__ void k_starts(const int* __restrict__ batch, int* __restrict__ starts) {
  int n = blockIdx.x * 256 + threadIdx.x;
  if (n >= NNODES) return;
  int b = batch[n];
  if (n == 0) { for (int bb = 0; bb <= b; ++bb) starts[bb] = 0; }
  else { int pb = batch[n - 1]; for (int bb = pb + 1; bb <= b; ++bb) starts[bb] = n; }
  if (n == NNODES - 1) { for (int bb = b + 1; bb <= BGR; ++bb) starts[bb] = NNODES; }
}

// ---------------- per-node softmax-aggregate (wave per node, split-wave bf16 gather)
__global__ __launch_bounds__(256) void k_aggr(
    const unsigned short* __restrict__ hb, const float* __restrict__ as_, const float* __restrict__ ad_,
    const int* __restrict__ cnt, const int* __restrict__ offs, const int* __restrict__ csr,
    const int* __restrict__ batch, const float* __restrict__ bias,
    float* __restrict__ pooled) {
  __shared__ float pacc[4][128];
  __shared__ uint2 sew[4][64];      // (src, weight-bits) packed
  __shared__ int wb[4];
  const int tid = threadIdx.x;
  const int w = tid >> 6, lane = tid & 63;
  const int half = lane >> 5, l5 = lane & 31;
  const int blk = blockIdx.x;
  const int t = blk / (NNODES / 4);
  const int n = (blk - t * (NNODES / 4)) * 4 + w;
  const int tn = t * NNODES + n;
  const int deg = cnt[tn];
  const int end = offs[tn];          // after scatter, offs holds segment end
  const int start = end - deg;
  const float adn = ad_[tn];
  const float wself = __expf(lrelu(as_[tn] + adn));
  const int* ecsr = csr + (size_t)t * NEDGES;
  const float* asb = as_ + (size_t)t * NNODES;
  const unsigned short* hbase = hb + (size_t)t * NNODES * HDIM;

  // self term: even half only (lane dims l5*4 .. l5*4+3)
  float acc0, acc1, acc2, acc3;
  if (half == 0) {
    uint2 u = *(const uint2*)(hbase + (size_t)n * HDIM + l5 * 4);
    acc0 = wself * bf_lo(u.x); acc1 = wself * bf_hi(u.x);
    acc2 = wself * bf_lo(u.y); acc3 = wself * bf_hi(u.y);
  } else { acc0 = acc1 = acc2 = acc3 = 0.f; }
  float sp = 0.f;

  for (int base = start; base < end; base += 64) {
    const int c = min(64, end - base);
    {
      int s = 0; float wv = 0.f;
      if (lane < c) { s = ecsr[base + lane]; wv = __expf(lrelu(asb[s] + adn)); }
      sew[w][lane] = make_uint2((unsigned int)s, __float_as_uint(wv));
      sp += wv;
    }
    // same-wave LDS produce->consume: program order within wave
    const int cp = (c + 1) & ~1;       // pad to pair (pad weight = 0)
    #pragma unroll 4
    for (int j = 0; j < cp; j += 2) {
      uint2 ew = sew[w][j + half];     // half 0 -> even edge, half 1 -> odd edge
      float wgt = __uint_as_float(ew.y);
      uint2 u = *(const uint2*)(hbase + (size_t)ew.x * HDIM + l5 * 4);
      acc0 += wgt * bf_lo(u.x); acc1 += wgt * bf_hi(u.x);
      acc2 += wgt * bf_lo(u.y); acc3 += wgt * bf_hi(u.y);
    }
  }
  #pragma unroll
  for (int o = 32; o > 0; o >>= 1) sp += __shfl_xor(sp, o);
  const float inv = 1.0f / (sp + wself);
  acc0 += __shfl_xor(acc0, 32);
  acc1 += __shfl_xor(acc1, 32);
  acc2 += __shfl_xor(acc2, 32);
  acc3 += __shfl_xor(acc3, 32);
  if (half == 0) {
    float4 bv = *(const float4*)(bias + l5 * 4);
    pacc[w][l5 * 4 + 0] = acc0 * inv + bv.x;
    pacc[w][l5 * 4 + 1] = acc1 * inv + bv.y;
    pacc[w][l5 * 4 + 2] = acc2 * inv + bv.z;
    pacc[w][l5 * 4 + 3] = acc3 * inv + bv.w;
  }
  if (lane == 0) wb[w] = batch[n];
  __syncthreads();
  // sorted-adjacent merge of the 4 node slots
  if (tid < 128 && wb[3] == wb[2]) pacc[2][tid] += pacc[3][tid];
  __syncthreads();
  if (tid < 128 && wb[2] == wb[1]) pacc[1][tid] += pacc[2][tid];
  __syncthreads();
  if (tid < 128 && wb[1] == wb[0]) pacc[0][tid] += pacc[1][tid];
  __syncthreads();
  #pragma unroll
  for (int it = tid; it < 512; it += 256) {
    int ww = it >> 7, d = it & 127;
    bool root = (ww == 0) || (wb[ww] != wb[ww - 1]);
    if (root) atomicAdd(&pooled[((size_t)t * BGR + wb[ww]) * HDIM + d], pacc[ww][d]);
  }
}

// ---------------- LSTM over T + fused FC (one block per batch row b)
// 512 threads = 1 gate each; weights STREAMED from L2 (identical rows across
// blocks -> L2-hot). No register arrays with runtime indices -> no spill.
__global__ __launch_bounds__(512) void k_lstm_fc(
    const float* __restrict__ pooled, const int* __restrict__ starts,
    const float* __restrict__ W_ih, const float* __restrict__ W_hh,
    const float* __restrict__ b_ih, const float* __restrict__ b_hh,
    const float* __restrict__ z, const float* __restrict__ fc_W,
    const float* __restrict__ fc_b, float* __restrict__ out) {
  const int b = blockIdx.x;
  const int g = threadIdx.x;   // gate index 0..511 (i,f,g,o blocks of 128)
  __shared__ float hv[128], cv[128], part[512];
  __shared__ float pool8[TT][128];
  __shared__ float fcp[16][17];
  const int cntb = starts[b + 1] - starts[b];
  const float invc = 1.0f / (float)max(cntb, 1);
  #pragma unroll
  for (int i = 0; i < 2; ++i) {
    int idx = g + i * 512;
    int t = idx >> 7, k = idx & 127;
    pool8[t][k] = pooled[((size_t)t * BGR + b) * HDIM + k] * invc;
  }
  if (g < 128) { hv[g] = 0.f; cv[g] = 0.f; }
  __syncthreads();

  // input-gate contributions for all 8 timesteps, one streaming pass over W_ih row
  float gx[8] = {};
  {
    const float4* wi = (const float4*)(W_ih + (size_t)g * HDIM);
    #pragma unroll
    for (int k4 = 0; k4 < 32; ++k4) {
      float4 wv = wi[k4];
      #pragma unroll
      for (int t = 0; t < TT; ++t) {
        float4 p = *(const float4*)(&pool8[t][k4 * 4]);
        gx[t] += wv.x * p.x + wv.y * p.y + wv.z * p.z + wv.w * p.w;
      }
    }
  }
  const float bsum = b_ih[g] + b_hh[g];
  const float4* wh = (const float4*)(W_hh + (size_t)g * HDIM);
  #pragma unroll
  for (int t = 0; t < TT; ++t) {
    float s = gx[t] + bsum;
    #pragma unroll
    for (int k4 = 0; k4 < 32; ++k4) {
      float4 wv = wh[k4];
      float4 hh = *(const float4*)(&hv[k4 * 4]);
      s += wv.x * hh.x + wv.y * hh.y + wv.z * hh.z + wv.w * hh.w;
    }
    part[g] = s;
    __syncthreads();
    if (g < 128) {
      float ig = sigmoidf(part[g]);
      float fg = sigmoidf(part[128 + g]);
      float gc = tanh_fast(part[256 + g]);
      float og = sigmoidf(part[384 + g]);
      float c = fg * cv[g] + ig * gc;
      cv[g] = c;
      hv[g] = og * tanh_fast(c);
    }
    __syncthreads();
  }
  // fused FC: out[b][c] = concat(hv, z[b]) . fc_W[c] + fc_b[c]
  if (g < 256) {
    const int c = g >> 4, kp = g & 15;
    float s = 0.f;
    for (int k = kp * 16; k < kp * 16 + 16; ++k) {
      float v = (k < 128) ? hv[k] : z[(size_t)b * HDIM + (k - 128)];
      s += v * fc_W[(size_t)c * 256 + k];
    }
    fcp[c][kp] = s;
  }
  __syncthreads();
  if (g < 16) {
    float r = fc_b[g];
    #pragma unroll
    for (int k = 0; k < 16; ++k) r += fcp[g][k];
    out[(size_t)b * NCLS + g] = r;
  }
}

extern "C" void kernel_launch(void* const* d_in, const int* in_sizes, int n_in,
                              void* d_out, int out_size, void* d_ws, size_t ws_size,
                              hipStream_t stream) {
  const float* x       = (const float*)d_in[0];
  const int*   ei      = (const int*)d_in[1];
  const int*   batch   = (const int*)d_in[2];
  const float* z       = (const float*)d_in[3];
  const float* gat_W   = (const float*)d_in[4];
  const float* att_src = (const float*)d_in[5];
  const float* att_dst = (const float*)d_in[6];
  const float* gat_bias= (const float*)d_in[7];
  const float* W_ih    = (const float*)d_in[8];
  const float* W_hh    = (const float*)d_in[9];
  const float* b_ih    = (const float*)d_in[10];
  const float* b_hh    = (const float*)d_in[11];
  const float* fc_W    = (const float*)d_in[12];
  const float* fc_b    = (const float*)d_in[13];
  float* out = (float*)d_out;

  char* ws = (char*)d_ws;
  size_t off = 0;
  auto alloc = [&](size_t bytes) {
    void* p = (void*)(ws + off);
    off += (bytes + 255) & ~(size_t)255;
    return p;
  };
  unsigned short* hbuf = (unsigned short*)alloc((size_t)TT * NNODES * HDIM * 2);  // 41 MB bf16
  float* as_    = (float*)alloc((size_t)TT * NNODES * 4);
  float* ad_    = (float*)alloc((size_t)TT * NNODES * 4);
  int*   cnt    = (int*)alloc((size_t)TT * NNODES * 4);
  int*   offs   = (int*)alloc((size_t)TT * NNODES * 4);
  int*   csr    = (int*)alloc((size_t)TT * NEDGES * 4);
  int*   starts = (int*)alloc((BGR + 1) * 4);
  float* pooled = (float*)alloc((size_t)TT * BGR * HDIM * 4);
  (void)ws_size; (void)in_sizes; (void)n_in; (void)out_size;

  hipMemsetAsync(cnt, 0, (size_t)TT * NNODES * 4, stream);
  hipMemsetAsync(pooled, 0, (size_t)TT * BGR * HDIM * 4, stream);

  k_gemm<<<(TT * NNODES) / GR, 256, 0, stream>>>(x, gat_W, att_src, att_dst, hbuf, as_, ad_);
  k_hist<<<(TT * NEDGES) / 256, 256, 0, stream>>>(ei, cnt);
  k_scan<<<TT, 256, 0, stream>>>(cnt, offs);
  k_scatter<<<(TT * NEDGES) / 256, 256, 0, stream>>>(ei, offs, csr);
  k_starts<<<(NNODES + 255) / 256, 256, 0, stream>>>(batch, starts);
  k_aggr<<<TT * (NNODES / 4), 256, 0, stream>>>(hbuf, as_, ad_, cnt, offs, csr, batch, gat_bias, pooled);
  k_lstm_fc<<<BGR, 512, 0, stream>>>(pooled, starts, W_ih, W_hh, b_ih, b_hh, z, fc_W, fc_b, out);
}

// Round 6
// 526.422 us; speedup vs baseline: 1.5031x; 1.2772x over previous
//
#include <hip/hip_runtime.h>
#include <math.h>

#define TT 8
#define NNODES 20000
#define NEDGES 320000
#define FDIM 128
#define HDIM 128
#define BGR 64
#define NCLS 16
#define GR 128   // gemm rows per block

__device__ __forceinline__ float lrelu(float x) { return fmaxf(x, 0.2f * x); }
__device__ __forceinline__ float sigmoidf(float x) { return 1.0f / (1.0f + __expf(-x)); }
__device__ __forceinline__ float tanh_fast(float x) {
  return 1.0f - 2.0f / (__expf(2.0f * x) + 1.0f);
}
__device__ __forceinline__ unsigned short f2bf(float f) {   // RNE
  unsigned int u = __float_as_uint(f);
  unsigned int r = (u + 0x7fff + ((u >> 16) & 1)) >> 16;
  return (unsigned short)r;
}
__device__ __forceinline__ float bf_lo(unsigned int u) { return __uint_as_float(u << 16); }
__device__ __forceinline__ float bf_hi(unsigned int u) { return __uint_as_float(u & 0xffff0000u); }

// ---------------- GEMM: h = x @ W (h stored bf16), epilogue: as=h@att_src, ad=h@att_dst
// 128x128 tile per block, 256 threads, 8x8 acc per thread.
__global__ __launch_bounds__(256) void k_gemm(
    const float* __restrict__ x, const float* __restrict__ W,
    const float* __restrict__ att_s, const float* __restrict__ att_d,
    unsigned short* __restrict__ hb, float* __restrict__ as_, float* __restrict__ ad_) {
  __shared__ float xsT[32][GR + 4];   // [k][row]
  __shared__ float ws[32][HDIM];      // [k][col]
  __shared__ float asl[GR], adl[GR];
  __shared__ float atts[HDIM], attd[HDIM];
  const int tid = threadIdx.x;
  const int row0 = blockIdx.x * GR;
  if (tid < GR) { asl[tid] = 0.f; adl[tid] = 0.f; }
  if (tid < 128) { atts[tid] = att_s[tid]; attd[tid] = att_d[tid]; }
  const int ty = tid >> 4;   // 0..15 -> 8 rows each
  const int tx = tid & 15;   // 0..15 -> 8 cols each
  float acc[8][8] = {};
  for (int kb = 0; kb < 4; ++kb) {
    __syncthreads();
    #pragma unroll
    for (int p = 0; p < 4; ++p) {   // x tile: 128 rows x 32 k, transposed store
      int idx = tid + p * 256;
      int r = idx >> 3, k4 = idx & 7;
      float4 v = *(const float4*)(x + (size_t)(row0 + r) * FDIM + kb * 32 + k4 * 4);
      xsT[k4 * 4 + 0][r] = v.x; xsT[k4 * 4 + 1][r] = v.y;
      xsT[k4 * 4 + 2][r] = v.z; xsT[k4 * 4 + 3][r] = v.w;
    }
    #pragma unroll
    for (int p = 0; p < 4; ++p) {   // W tile
      int kr = (tid >> 5) + p * 8;
      int c4 = (tid & 31) * 4;
      *(float4*)(&ws[kr][c4]) = *(const float4*)(W + (size_t)(kb * 32 + kr) * HDIM + c4);
    }
    __syncthreads();
    #pragma unroll
    for (int k = 0; k < 32; ++k) {
      float a[8], bb[8];
      *(float4*)&a[0]  = *(const float4*)(&xsT[k][ty * 8]);
      *(float4*)&a[4]  = *(const float4*)(&xsT[k][ty * 8 + 4]);
      *(float4*)&bb[0] = *(const float4*)(&ws[k][tx * 8]);
      *(float4*)&bb[4] = *(const float4*)(&ws[k][tx * 8 + 4]);
      #pragma unroll
      for (int i = 0; i < 8; ++i)
        #pragma unroll
        for (int j = 0; j < 8; ++j)
          acc[i][j] += a[i] * bb[j];
    }
  }
  float av[8], dv[8];
  *(float4*)&av[0] = *(const float4*)(&atts[tx * 8]);
  *(float4*)&av[4] = *(const float4*)(&atts[tx * 8 + 4]);
  *(float4*)&dv[0] = *(const float4*)(&attd[tx * 8]);
  *(float4*)&dv[4] = *(const float4*)(&attd[tx * 8 + 4]);
  #pragma unroll
  for (int i = 0; i < 8; ++i) {
    int row = row0 + ty * 8 + i;
    float ps = 0.f, pd = 0.f;
    #pragma unroll
    for (int j = 0; j < 8; ++j) { ps += acc[i][j] * av[j]; pd += acc[i][j] * dv[j]; }
    uint4 pk;
    pk.x = (unsigned int)f2bf(acc[i][0]) | ((unsigned int)f2bf(acc[i][1]) << 16);
    pk.y = (unsigned int)f2bf(acc[i][2]) | ((unsigned int)f2bf(acc[i][3]) << 16);
    pk.z = (unsigned int)f2bf(acc[i][4]) | ((unsigned int)f2bf(acc[i][5]) << 16);
    pk.w = (unsigned int)f2bf(acc[i][6]) | ((unsigned int)f2bf(acc[i][7]) << 16);
    *(uint4*)(hb + (size_t)row * HDIM + tx * 8) = pk;
    atomicAdd(&asl[ty * 8 + i], ps);
    atomicAdd(&adl[ty * 8 + i], pd);
  }
  __syncthreads();
  if (tid < GR) { as_[row0 + tid] = asl[tid]; ad_[row0 + tid] = adl[tid]; }
}

// ---------------- CSR build
__global__ void k_hist(const int* __restrict__ ei, int* __restrict__ cnt) {
  int g = blockIdx.x * 256 + threadIdx.x;
  int t = g / NEDGES, e = g - t * NEDGES;
  int dst = ei[(size_t)t * 2 * NEDGES + NEDGES + e];
  atomicAdd(&cnt[t * NNODES + dst], 1);
}

__global__ __launch_bounds__(256) void k_scan(const int* __restrict__ cnt, int* __restrict__ offs) {
  const int t = blockIdx.x;
  const int tid = threadIdx.x;
  const int SPAN = 79;
  __shared__ int sums[256];
  int lo = tid * SPAN, hi = min(lo + SPAN, NNODES);
  int s = 0;
  for (int i = lo; i < hi; ++i) s += cnt[t * NNODES + i];
  sums[tid] = s;
  __syncthreads();
  for (int off = 1; off < 256; off <<= 1) {
    int add = (tid >= off) ? sums[tid - off] : 0;
    __syncthreads();
    sums[tid] += add;
    __syncthreads();
  }
  int run = sums[tid] - s;
  for (int i = lo; i < hi; ++i) { offs[t * NNODES + i] = run; run += cnt[t * NNODES + i]; }
}

__global__ void k_scatter(const int* __restrict__ ei, int* __restrict__ offs, int* __restrict__ csr) {
  int g = blockIdx.x * 256 + threadIdx.x;
  int t = g / NEDGES, e = g - t * NEDGES;
  int src = ei[(size_t)t * 2 * NEDGES + e];
  int dst = ei[(size_t)t * 2 * NEDGES + NEDGES + e];
  int pos = atomicAdd(&offs[t * NNODES + dst], 1);
  csr[(size_t)t * NEDGES + pos] = src;
}

// ---------------- batch segment starts (batch is sorted)
__global__ void k_starts(const int* __restrict__ batch, int* __restrict__ starts) {
  int n = blockIdx.x * 256 + threadIdx.x;
  if (n >= NNODES) return;
  int b = batch[n];
  if (n == 0) { for (int bb = 0; bb <= b; ++bb) starts[bb] = 0; }
  else { int pb = batch[n - 1]; for (int bb = pb + 1; bb <= b; ++bb) starts[bb] = n; }
  if (n == NNODES - 1) { for (int bb = b + 1; bb <= BGR; ++bb) starts[bb] = NNODES; }
}

// ---------------- per-node softmax-aggregate (wave per node, split-wave bf16 gather)
__global__ __launch_bounds__(256) void k_aggr(
    const unsigned short* __restrict__ hb, const float* __restrict__ as_, const float* __restrict__ ad_,
    const int* __restrict__ cnt, const int* __restrict__ offs, const int* __restrict__ csr,
    const int* __restrict__ batch, const float* __restrict__ bias,
    float* __restrict__ pooled) {
  __shared__ float pacc[4][128];
  __shared__ uint2 sew[4][64];      // (src, weight-bits) packed
  __shared__ int wb[4];
  const int tid = threadIdx.x;
  const int w = tid >> 6, lane = tid & 63;
  const int half = lane >> 5, l5 = lane & 31;
  const int blk = blockIdx.x;
  const int t = blk / (NNODES / 4);
  const int n = (blk - t * (NNODES / 4)) * 4 + w;
  const int tn = t * NNODES + n;
  const int deg = cnt[tn];
  const int end = offs[tn];          // after scatter, offs holds segment end
  const int start = end - deg;
  const float adn = ad_[tn];
  const float wself = __expf(lrelu(as_[tn] + adn));
  const int* ecsr = csr + (size_t)t * NEDGES;
  const float* asb = as_ + (size_t)t * NNODES;
  const unsigned short* hbase = hb + (size_t)t * NNODES * HDIM;

  // self term: even half only (lane dims l5*4 .. l5*4+3)
  float acc0, acc1, acc2, acc3;
  if (half == 0) {
    uint2 u = *(const uint2*)(hbase + (size_t)n * HDIM + l5 * 4);
    acc0 = wself * bf_lo(u.x); acc1 = wself * bf_hi(u.x);
    acc2 = wself * bf_lo(u.y); acc3 = wself * bf_hi(u.y);
  } else { acc0 = acc1 = acc2 = acc3 = 0.f; }
  float sp = 0.f;

  for (int base = start; base < end; base += 64) {
    const int c = min(64, end - base);
    {
      int s = 0; float wv = 0.f;
      if (lane < c) { s = ecsr[base + lane]; wv = __expf(lrelu(asb[s] + adn)); }
      sew[w][lane] = make_uint2((unsigned int)s, __float_as_uint(wv));
      sp += wv;
    }
    // same-wave LDS produce->consume: program order within wave
    const int cp = (c + 1) & ~1;       // pad to pair (pad weight = 0)
    #pragma unroll 4
    for (int j = 0; j < cp; j += 2) {
      uint2 ew = sew[w][j + half];     // half 0 -> even edge, half 1 -> odd edge
      float wgt = __uint_as_float(ew.y);
      uint2 u = *(const uint2*)(hbase + (size_t)ew.x * HDIM + l5 * 4);
      acc0 += wgt * bf_lo(u.x); acc1 += wgt * bf_hi(u.x);
      acc2 += wgt * bf_lo(u.y); acc3 += wgt * bf_hi(u.y);
    }
  }
  #pragma unroll
  for (int o = 32; o > 0; o >>= 1) sp += __shfl_xor(sp, o);
  const float inv = 1.0f / (sp + wself);
  acc0 += __shfl_xor(acc0, 32);
  acc1 += __shfl_xor(acc1, 32);
  acc2 += __shfl_xor(acc2, 32);
  acc3 += __shfl_xor(acc3, 32);
  if (half == 0) {
    float4 bv = *(const float4*)(bias + l5 * 4);
    pacc[w][l5 * 4 + 0] = acc0 * inv + bv.x;
    pacc[w][l5 * 4 + 1] = acc1 * inv + bv.y;
    pacc[w][l5 * 4 + 2] = acc2 * inv + bv.z;
    pacc[w][l5 * 4 + 3] = acc3 * inv + bv.w;
  }
  if (lane == 0) wb[w] = batch[n];
  __syncthreads();
  // sorted-adjacent merge of the 4 node slots
  if (tid < 128 && wb[3] == wb[2]) pacc[2][tid] += pacc[3][tid];
  __syncthreads();
  if (tid < 128 && wb[2] == wb[1]) pacc[1][tid] += pacc[2][tid];
  __syncthreads();
  if (tid < 128 && wb[1] == wb[0]) pacc[0][tid] += pacc[1][tid];
  __syncthreads();
  #pragma unroll
  for (int it = tid; it < 512; it += 256) {
    int ww = it >> 7, d = it & 127;
    bool root = (ww == 0) || (wb[ww] != wb[ww - 1]);
    if (root) atomicAdd(&pooled[((size_t)t * BGR + wb[ww]) * HDIM + d], pacc[ww][d]);
  }
}

// ---------------- LSTM over T + fused FC (one block per batch row b)
// 512 threads = 1 gate each. W_hh staged ONCE into LDS as packed bf16 pairs,
// row stride 65 uints -> both write and read hit 2 lanes/bank (conflict-free).
// Recurrence reads only LDS; no weight register arrays -> no spill possible.
__global__ __launch_bounds__(512) void k_lstm_fc(
    const float* __restrict__ pooled, const int* __restrict__ starts,
    const float* __restrict__ W_ih, const float* __restrict__ W_hh,
    const float* __restrict__ b_ih, const float* __restrict__ b_hh,
    const float* __restrict__ z, const float* __restrict__ fc_W,
    const float* __restrict__ fc_b, float* __restrict__ out) {
  const int b = blockIdx.x;
  const int g = threadIdx.x;   // gate index 0..511 (i,f,g,o blocks of 128)
  __shared__ unsigned int wpk[512 * 65];   // 133.1 KB packed bf16 W_hh
  __shared__ float hv[128], cv[128], part[512];
  __shared__ float pool8[TT][128];
  __shared__ float fcp[16][17];

  // one-time stage: W_hh row gr, pair j -> wpk[gr*65+j]
  // global: lanes cover one row's 64 float2 = 512B contiguous (coalesced)
  // LDS write bank = (gr + j) % 32 -> 2 lanes/bank (free)
  #pragma unroll 2
  for (int it = 0; it < 64; ++it) {
    int i = g + it * 512;            // 0..32767
    int gr = i >> 6, j = i & 63;
    float2 wv = *(const float2*)(W_hh + (size_t)gr * HDIM + j * 2);
    wpk[gr * 65 + j] = (unsigned int)f2bf(wv.x) | ((unsigned int)f2bf(wv.y) << 16);
  }

  const int cntb = starts[b + 1] - starts[b];
  const float invc = 1.0f / (float)max(cntb, 1);
  #pragma unroll
  for (int i = 0; i < 2; ++i) {
    int idx = g + i * 512;
    int t = idx >> 7, k = idx & 127;
    pool8[t][k] = pooled[((size_t)t * BGR + b) * HDIM + k] * invc;
  }
  if (g < 128) { hv[g] = 0.f; cv[g] = 0.f; }
  __syncthreads();

  // input contributions for all 8 timesteps: one fp32 pass over W_ih row
  // (unroll 2 caps in-flight global loads -> no register blowup)
  float gx[8] = {};
  {
    const float4* wi = (const float4*)(W_ih + (size_t)g * HDIM);
    #pragma unroll 2
    for (int k4 = 0; k4 < 32; ++k4) {
      float4 wv = wi[k4];
      #pragma unroll
      for (int t = 0; t < TT; ++t) {
        float4 p = *(const float4*)(&pool8[t][k4 * 4]);
        gx[t] += wv.x * p.x + wv.y * p.y + wv.z * p.z + wv.w * p.w;
      }
    }
  }
  const float bsum = b_ih[g] + b_hh[g];
  const unsigned int* wr = &wpk[g * 65];
  const float4* hv4 = (const float4*)hv;
  #pragma unroll
  for (int t = 0; t < TT; ++t) {
    float s = gx[t] + bsum;
    #pragma unroll 8
    for (int j2 = 0; j2 < 32; ++j2) {
      unsigned int w0 = wr[2 * j2], w1 = wr[2 * j2 + 1];
      float4 hh = hv4[j2];
      s += bf_lo(w0) * hh.x + bf_hi(w0) * hh.y + bf_lo(w1) * hh.z + bf_hi(w1) * hh.w;
    }
    part[g] = s;
    __syncthreads();
    if (g < 128) {
      float ig = sigmoidf(part[g]);
      float fg = sigmoidf(part[128 + g]);
      float gc = tanh_fast(part[256 + g]);
      float og = sigmoidf(part[384 + g]);
      float c = fg * cv[g] + ig * gc;
      cv[g] = c;
      hv[g] = og * tanh_fast(c);
    }
    __syncthreads();
  }
  // fused FC: out[b][c] = concat(hv, z[b]) . fc_W[c] + fc_b[c]
  if (g < 256) {
    const int c = g >> 4, kp = g & 15;
    float s = 0.f;
    for (int k = kp * 16; k < kp * 16 + 16; ++k) {
      float v = (k < 128) ? hv[k] : z[(size_t)b * HDIM + (k - 128)];
      s += v * fc_W[(size_t)c * 256 + k];
    }
    fcp[c][kp] = s;
  }
  __syncthreads();
  if (g < 16) {
    float r = fc_b[g];
    #pragma unroll
    for (int k = 0; k < 16; ++k) r += fcp[g][k];
    out[(size_t)b * NCLS + g] = r;
  }
}

extern "C" void kernel_launch(void* const* d_in, const int* in_sizes, int n_in,
                              void* d_out, int out_size, void* d_ws, size_t ws_size,
                              hipStream_t stream) {
  const float* x       = (const float*)d_in[0];
  const int*   ei      = (const int*)d_in[1];
  const int*   batch   = (const int*)d_in[2];
  const float* z       = (const float*)d_in[3];
  const float* gat_W   = (const float*)d_in[4];
  const float* att_src = (const float*)d_in[5];
  const float* att_dst = (const float*)d_in[6];
  const float* gat_bias= (const float*)d_in[7];
  const float* W_ih    = (const float*)d_in[8];
  const float* W_hh    = (const float*)d_in[9];
  const float* b_ih    = (const float*)d_in[10];
  const float* b_hh    = (const float*)d_in[11];
  const float* fc_W    = (const float*)d_in[12];
  const float* fc_b    = (const float*)d_in[13];
  float* out = (float*)d_out;

  char* ws = (char*)d_ws;
  size_t off = 0;
  auto alloc = [&](size_t bytes) {
    void* p = (void*)(ws + off);
    off += (bytes + 255) & ~(size_t)255;
    return p;
  };
  unsigned short* hbuf = (unsigned short*)alloc((size_t)TT * NNODES * HDIM * 2);  // 41 MB bf16
  float* as_    = (float*)alloc((size_t)TT * NNODES * 4);
  float* ad_    = (float*)alloc((size_t)TT * NNODES * 4);
  int*   cnt    = (int*)alloc((size_t)TT * NNODES * 4);
  int*   offs   = (int*)alloc((size_t)TT * NNODES * 4);
  int*   csr    = (int*)alloc((size_t)TT * NEDGES * 4);
  int*   starts = (int*)alloc((BGR + 1) * 4);
  float* pooled = (float*)alloc((size_t)TT * BGR * HDIM * 4);
  (void)ws_size; (void)in_sizes; (void)n_in; (void)out_size;

  hipMemsetAsync(cnt, 0, (size_t)TT * NNODES * 4, stream);
  hipMemsetAsync(pooled, 0, (size_t)TT * BGR * HDIM * 4, stream);

  k_gemm<<<(TT * NNODES) / GR, 256, 0, stream>>>(x, gat_W, att_src, att_dst, hbuf, as_, ad_);
  k_hist<<<(TT * NEDGES) / 256, 256, 0, stream>>>(ei, cnt);
  k_scan<<<TT, 256, 0, stream>>>(cnt, offs);
  k_scatter<<<(TT * NEDGES) / 256, 256, 0, stream>>>(ei, offs, csr);
  k_starts<<<(NNODES + 255) / 256, 256, 0, stream>>>(batch, starts);
  k_aggr<<<TT * (NNODES / 4), 256, 0, stream>>>(hbuf, as_, ad_, cnt, offs, csr, batch, gat_bias, pooled);
  k_lstm_fc<<<BGR, 512, 0, stream>>>(pooled, starts, W_ih, W_hh, b_ih, b_hh, z, fc_W, fc_b, out);
}